// Round 9
// baseline (183.415 us; speedup 1.0000x reference)
//
#include <hip/hip_runtime.h>

// LearnedTaskSpecificLinear: out[n,o] = sum_i x[n,i] * W[task_ids[n], i, o]
// x: [2048,512] f32, task_ids: [2048] i32, W: [64,512,512] f32, out: [2048,512] f32
//
// Round 13: FULLY-CONTIGUOUS W streaming - one block per task.
//   R5-R12 all pinned at ~23 us (~3.1 TB/s effective) across schedule, barrier,
//   occupancy, and granule variants; fills hit 6.3 TB/s contiguous. Decisive
//   test of access-pattern theory: each block owns one task and streams the
//   task's ENTIRE 1 MB W slab SEQUENTIALLY (8 K-slabs x [64 k x 512 cols],
//   each slab a contiguous 128 KB read) through double-buffered LDS,
//   accumulating output in registers across slabs. No split-K, no atomics.
//   grid 64 x 512 thr (8 waves), 1 block/CU. LDS: Wt[2][512*64] f16 (128 KB)
//   + rl[2048] u16 (4 KB) = 132 KB.
//   Wave (rg = wv>>1 in 0..3, cq = wv&1): 16 rows (batch + rg*16) x 256 cols.
//   acc[16] f32x4 (64 VGPR) persists across all 8 slabs. Batch loop (64 rows)
//   re-streams W only in the ~never case cnt>64 (correct for any distribution).
//   Staging: thread t -> col-group cg=t&127 (4 cols), ot=t>>7 -> octets ot,ot+4;
//   slab = 16 float4 loads/thread; f32->f16 + XOR-swizzled write po=oct^(c&7)
//   (verified R5-R12 scheme, SLABK=64). Schedule: issue slab s+2 while staging
//   s+1 while MFMAing s; one lgkm-only barrier per slab (no vmcnt drain).
//   Register audit (R6 lesson): wb 64 + acc 64 + af 8 + xa 16 + misc ~30 = ~182
//   peak < 256 cap @ launch_bounds(512,2). tvv 32 dies after scan.

#define NDIM  512
#define KDIM  512
#define SLABK 64
#define NSLAB 8
#define LISTCAP 2048

typedef _Float16 f16x8 __attribute__((ext_vector_type(8)));
typedef float    f32x4 __attribute__((ext_vector_type(4)));
typedef int      i32x4 __attribute__((ext_vector_type(4)));

__global__ __launch_bounds__(512, 2) void k_task(
    const float* __restrict__ x,
    const int*   __restrict__ tids,
    const float* __restrict__ W,
    float*       __restrict__ out,
    int n_rows)
{
    const int tid  = threadIdx.x;      // 0..511
    const int lane = tid & 63;
    const int wv   = tid >> 6;         // 0..7
    const int ml   = lane & 15;
    const int q    = lane >> 4;
    const int rg   = wv >> 1;          // rowgroup 0..3 within 64-row batch
    const int cq   = wv & 1;           // col-half 0..1 (256 cols)

    const int cg   = tid & 127;        // staging col-group (4 cols)
    const int ot   = tid >> 7;         // staging octet base 0..3 (octets ot, ot+4)

    const int task = blockIdx.x;
    const float* Wg = W + (size_t)task * KDIM * NDIM;

    __shared__ __align__(16) _Float16 Wt[2][NDIM * SLABK];  // 2 x 64 KB
    __shared__ unsigned short rl[LISTCAP];                  // 4 KB

    // ---- staging helpers -------------------------------------------------
    // Slab s = W rows [s*64, s*64+64), all 512 cols: 128 KB CONTIGUOUS.
    // Per thread: 16 float4 (rows oct*8+j of k, cols 4cg..4cg+3).
    float4 wb[16];
    auto issueSlab = [&](int s) {
        const float* base = Wg + (size_t)(s * SLABK) * NDIM + cg * 4;
        #pragma unroll
        for (int st = 0; st < 2; ++st) {
            const int oct = ot + st * 4;
            #pragma unroll
            for (int j = 0; j < 8; ++j)
                wb[st * 8 + j] = *(const float4*)(base + (size_t)(oct * 8 + j) * NDIM);
        }
    };
    auto stageSlab = [&](int b) {      // f32->f16 + swizzled LDS write
        #pragma unroll
        for (int st = 0; st < 2; ++st) {
            const int oct = ot + st * 4;
            #pragma unroll
            for (int j2 = 0; j2 < 4; ++j2) {
                f16x8 h8;
                #pragma unroll
                for (int j = 0; j < 8; ++j)
                    h8[j] = (_Float16)(((const float*)&wb[st * 8 + j])[j2]);
                const int c  = cg * 4 + j2;
                const int po = oct ^ (c & 7);
                *(f16x8*)&Wt[b][c * SLABK + po * 8] = h8;
            }
        }
    };

    // ---- issue slab 0 FIRST (oldest in queue), then tids -----------------
    issueSlab(0);

    i32x4 tvv[8];
    #pragma unroll
    for (int cb = 0; cb < 8; ++cb) {
        const int r4 = cb * 256 + lane * 4;
        if (r4 + 3 < n_rows) {
            tvv[cb] = *(const i32x4*)(tids + r4);
        } else {
            #pragma unroll
            for (int j = 0; j < 4; ++j)
                tvv[cb][j] = (r4 + j < n_rows) ? tids[r4 + j] : -1;
        }
    }

    // ---- full-range ballot scan (every wave builds the identical list;
    // racing identical writes to rl are benign; runs under slab-0 latency)
    int cnt = 0;
    #pragma unroll
    for (int cb = 0; cb < 8; ++cb) {
        #pragma unroll
        for (int j = 0; j < 4; ++j) {
            const bool m = (tvv[cb][j] == task);
            const unsigned long long bal = __ballot(m);
            const int rank = __popcll(bal & ((1ull << lane) - 1ull));
            const int slot = cnt + rank;
            if (m && slot < LISTCAP) rl[slot] = (unsigned short)(cb * 256 + lane * 4 + j);
            cnt += __popcll(bal);
        }
    }

    if (cnt == 0) return;   // uniform across all waves: no barrier crossed

    // ---- batch loop over 64-row groups (1 batch in practice: P(cnt>64)~1e-7)
    for (int g0B = 0; g0B < cnt; g0B += 64) {
        if (g0B > 0) issueSlab(0);     // re-stream W for overflow batches

        const int gpos = g0B + rg * 16 + ml;
        const int row  = rl[(gpos < cnt) ? gpos : (cnt - 1)];
        const float* xr = x + (size_t)row * KDIM;

        f32x4 acc[16];
        #pragma unroll
        for (int ct = 0; ct < 16; ++ct) acc[ct] = (f32x4){};

        stageSlab(0);                  // waits slab-0 loads
        issueSlab(1);                  // slab 1 in flight across the barrier
        asm volatile("s_waitcnt lgkmcnt(0)" ::: "memory");
        __builtin_amdgcn_s_barrier();
        __builtin_amdgcn_sched_barrier(0);

        #pragma unroll
        for (int s = 0; s < NSLAB; ++s) {
            const int b = s & 1;

            // x A-fragments for this slab (row is L2-resident after 1st touch)
            f32x4 xa[4];
            #pragma unroll
            for (int ks = 0; ks < 2; ++ks) {
                xa[2 * ks]     = *(const f32x4*)(xr + s * SLABK + ks * 32 + q * 8);
                xa[2 * ks + 1] = *(const f32x4*)(xr + s * SLABK + ks * 32 + q * 8 + 4);
            }
            f16x8 af[2];
            #pragma unroll
            for (int ks = 0; ks < 2; ++ks) {
                f16x8 t8;
                const float* a0 = (const float*)&xa[2 * ks];
                #pragma unroll
                for (int j = 0; j < 8; ++j) t8[j] = (_Float16)a0[j];
                af[ks] = t8;
            }

            // 32 MFMAs over 16 col-tiles x 2 k-steps
            #pragma unroll
            for (int ks = 0; ks < 2; ++ks) {
                #pragma unroll
                for (int ct = 0; ct < 16; ++ct) {
                    const int cB = cq * 256 + ct * 16 + ml;
                    const int po = (ks * 4 + q) ^ (cB & 7);
                    const f16x8 bf = *(const f16x8*)&Wt[b][cB * SLABK + po * 8];
                    acc[ct] = __builtin_amdgcn_mfma_f32_16x16x32_f16(af[ks], bf, acc[ct], 0, 0, 0);
                }
            }

            if (s + 1 < NSLAB) {
                stageSlab((s + 1) & 1);            // waits slab s+1 loads
                if (s + 2 < NSLAB) issueSlab(s + 2); // keep stream going
                asm volatile("s_waitcnt lgkmcnt(0)" ::: "memory");
                __builtin_amdgcn_s_barrier();
                __builtin_amdgcn_sched_barrier(0);
            }
        }

        // ---- store: C/D row = q*4+rgi, col = ct*16+ml (verified mapping)
        #pragma unroll
        for (int rgi = 0; rgi < 4; ++rgi) {
            const int pos = g0B + rg * 16 + q * 4 + rgi;
            if (pos < cnt) {
                float* op = out + (size_t)rl[pos] * NDIM + cq * 256 + ml;
                #pragma unroll
                for (int ct = 0; ct < 16; ++ct)
                    op[ct * 16] = acc[ct][rgi];
            }
        }

        // batch boundary: next batch re-stages buf0; all compute of this batch
        // is done (stores are VMEM, no LDS hazard), but ensure no wave races
        // ahead into stageSlab(0) while another still reads Wt[1] above.
        if (g0B + 64 < cnt) {
            asm volatile("s_waitcnt lgkmcnt(0)" ::: "memory");
            __builtin_amdgcn_s_barrier();
            __builtin_amdgcn_sched_barrier(0);
        }
    }
}

extern "C" void kernel_launch(void* const* d_in, const int* in_sizes, int n_in,
                              void* d_out, int out_size, void* d_ws, size_t ws_size,
                              hipStream_t stream) {
    const float* x    = (const float*)d_in[0];
    const int*   tids = (const int*)d_in[1];
    const float* W    = (const float*)d_in[2];
    float*       out  = (float*)d_out;
    const int n_rows  = in_sizes[1];   // 2048

    k_task<<<dim3(64), dim3(512), 0, stream>>>(x, tids, W, out, n_rows);
}

// Round 11
// 109.878 us; speedup vs baseline: 1.6693x; 1.6693x over previous
//
#include <hip/hip_runtime.h>

// LearnedTaskSpecificLinear: out[n,o] = sum_i x[n,i] * W[task_ids[n], i, o]
// x: [2048,512] f32, task_ids: [2048] i32, W: [64,512,512] f32, out: [2048,512] f32
//
// Round 14b: re-run of Round 14 (bench died to an infra/container failure,
// not a kernel verdict; barrier/loop/memory audit found no hang risk —
// same precedent as R8/R8b).
//
// Clean split-K contiguity test (R13 retried without its confounds).
//   R13 was confounded by (a) VGPR spill [(512,2) empirically caps VGPR at 128;
//   cap = 256/min_waves across R9/R11/R13] and (b) 64-block grid [64/256 CUs
//   -> ~1.6 TB/s chip ceiling]. This round: full chip + hard reg discipline.
//   Main kernel k_split: 256 blocks x 512 thr, 1 block/CU (LDS 132 KB).
//   Block = (task, K-quarter): kq = bid>>6, task = bid&63 (task's 4 blocks on
//   one XCD since 64%8==0 -> shared x rows are L2-hits). W read = rows
//   [kq*128, kq*128+128) x all 512 cols = 256 KB FULLY CONTIGUOUS per block.
//   Both 64k-slabs of the quarter stay resident in LDS Wt[2][512*64] f16
//   (128 KB) -> ONE barrier total; batch loop (32 rows/batch: 8 waves =
//   2 rowgroups x 4 col-quarters, acc 8 x f32x4 = 32 VGPR) has no barriers.
//   Partials: ws[kq][row][col] f32 (16 MB of d_ws; every row is written by
//   its task's 4 blocks -> no zero-init). k_reduce sums the 4 partials
//   (BW-bound, ws likely L3-hot).
//   Staging: thread t: col-group cg = t&127 (4 cols), oq = t>>7 -> octets
//   {oq, oq+4} per slab; 8 float4/unit; 2-buffer rotation (wbA/wbB);
//   f32->f16 + XOR-swizzled write po = oct ^ (c&7) (verified R5-R13 scheme,
//   SLABK=64 read pattern identical to R13's verified mapping).
//   Register audit (corrected cap model): launch_bounds(512,1) -> no
//   artificial cap; peak ~130 (wbA32+wbB32+tvv32+addr), compute ~80. <=256
//   keeps 2 waves/SIMD. Spill tripwire: k_split WRITE >> 17 MB.

#define NDIM  512
#define KDIM  512
#define KQ    128
#define SLABK 64
#define LISTCAP 2048

typedef _Float16 f16x8 __attribute__((ext_vector_type(8)));
typedef float    f32x4 __attribute__((ext_vector_type(4)));
typedef int      i32x4 __attribute__((ext_vector_type(4)));

__global__ __launch_bounds__(512, 1) void k_split(
    const float* __restrict__ x,
    const int*   __restrict__ tids,
    const float* __restrict__ W,
    float*       __restrict__ ws,
    int n_rows)
{
    const int tid  = threadIdx.x;      // 0..511
    const int lane = tid & 63;
    const int wv   = tid >> 6;         // 0..7
    const int ml   = lane & 15;
    const int q    = lane >> 4;
    const int rg   = wv >> 2;          // rowgroup 0..1 within 32-row batch
    const int cw   = wv & 3;           // col-quarter 0..3 (128 cols)

    const int cg   = tid & 127;        // staging col-group (4 cols)
    const int oq   = tid >> 7;         // 0..3 -> octets {oq, oq+4} per slab

    const int kq   = blockIdx.x >> 6;  // K-quarter 0..3
    const int task = blockIdx.x & 63;  // task's 4 blocks share bid%8 -> one XCD

    const float* Wq = W + (size_t)task * KDIM * NDIM + (size_t)kq * KQ * NDIM;

    __shared__ __align__(16) _Float16 Wt[2][NDIM * SLABK];  // 128 KB (full quarter)
    __shared__ unsigned short rl[LISTCAP];                  // 4 KB

    // ---- staging: unit (s, u) = slab s, octet oq + u*4; 8 float4/thread
    float4 wbA[8], wbB[8];
    auto issueU = [&](int s, int u, float4 (&wb)[8]) {
        const float* base = Wq + (size_t)(s * SLABK + (oq + u * 4) * 8) * NDIM + cg * 4;
        #pragma unroll
        for (int j = 0; j < 8; ++j)
            wb[j] = *(const float4*)(base + (size_t)j * NDIM);
    };
    auto stageU = [&](int s, int u, const float4 (&wb)[8]) {
        const int oct = oq + u * 4;
        #pragma unroll
        for (int j2 = 0; j2 < 4; ++j2) {
            f16x8 h8;
            #pragma unroll
            for (int j = 0; j < 8; ++j)
                h8[j] = (_Float16)(((const float*)&wb[j])[j2]);
            const int c  = cg * 4 + j2;
            const int po = oct ^ (c & 7);
            *(f16x8*)&Wt[s][c * SLABK + po * 8] = h8;
        }
    };

    // ---- issue slab 0 (both units) first: oldest in queue
    issueU(0, 0, wbA);
    issueU(0, 1, wbB);

    // ---- tids preload + full-range ballot scan (all waves identical; benign
    // identical rl races; same-wave rl reads ordered by lgkmcnt)
    i32x4 tvv[8];
    #pragma unroll
    for (int cb = 0; cb < 8; ++cb) {
        const int r4 = cb * 256 + lane * 4;
        if (r4 + 3 < n_rows) {
            tvv[cb] = *(const i32x4*)(tids + r4);
        } else {
            #pragma unroll
            for (int j = 0; j < 4; ++j)
                tvv[cb][j] = (r4 + j < n_rows) ? tids[r4 + j] : -1;
        }
    }
    int cnt = 0;
    #pragma unroll
    for (int cb = 0; cb < 8; ++cb) {
        #pragma unroll
        for (int j = 0; j < 4; ++j) {
            const bool m = (tvv[cb][j] == task);
            const unsigned long long bal = __ballot(m);
            const int rank = __popcll(bal & ((1ull << lane) - 1ull));
            const int slot = cnt + rank;
            if (m && slot < LISTCAP) rl[slot] = (unsigned short)(cb * 256 + lane * 4 + j);
            cnt += __popcll(bal);
        }
    }

    // ---- 2-buffer staging stream (slab 1 issued while slab 0 stages)
    stageU(0, 0, wbA); issueU(1, 0, wbA);
    stageU(0, 1, wbB); issueU(1, 1, wbB);
    stageU(1, 0, wbA);
    stageU(1, 1, wbB);

    asm volatile("s_waitcnt lgkmcnt(0)" ::: "memory");
    __builtin_amdgcn_s_barrier();      // the ONLY barrier
    __builtin_amdgcn_sched_barrier(0);

    if (cnt == 0) return;              // uniform across block

    // ---- batch loop: 32 rows/batch, both slabs resident, no barriers
    for (int g0 = 0; g0 < cnt; g0 += 32) {
        const int gpos = g0 + rg * 16 + ml;
        const int row  = rl[(gpos < cnt) ? gpos : (cnt - 1)];
        const float* xr = x + (size_t)row * KDIM + kq * KQ;

        // x A-fragments for this K-quarter (4 x f16x8 = 128 k)
        f16x8 af[4];
        #pragma unroll
        for (int c32 = 0; c32 < 4; ++c32) {
            f32x4 xa0 = *(const f32x4*)(xr + c32 * 32 + q * 8);
            f32x4 xa1 = *(const f32x4*)(xr + c32 * 32 + q * 8 + 4);
            f16x8 t8;
            #pragma unroll
            for (int j = 0; j < 4; ++j) t8[j]     = (_Float16)xa0[j];
            #pragma unroll
            for (int j = 0; j < 4; ++j) t8[4 + j] = (_Float16)xa1[j];
            af[c32] = t8;
        }

        f32x4 acc[8];
        #pragma unroll
        for (int ct = 0; ct < 8; ++ct) acc[ct] = (f32x4){};

        #pragma unroll
        for (int s = 0; s < 2; ++s) {
            #pragma unroll
            for (int ks = 0; ks < 2; ++ks) {
                #pragma unroll
                for (int ct = 0; ct < 8; ++ct) {
                    const int cB = cw * 128 + ct * 16 + ml;
                    const int po = (ks * 4 + q) ^ (cB & 7);
                    const f16x8 bf = *(const f16x8*)&Wt[s][cB * SLABK + po * 8];
                    acc[ct] = __builtin_amdgcn_mfma_f32_16x16x32_f16(af[s * 2 + ks], bf, acc[ct], 0, 0, 0);
                }
            }
        }

        // partial store: ws[kq][row][cw*128 + ct*16 + ml]
        #pragma unroll
        for (int rgi = 0; rgi < 4; ++rgi) {
            const int pos = g0 + rg * 16 + q * 4 + rgi;
            if (pos < cnt) {
                float* op = ws + ((size_t)kq * n_rows + rl[pos]) * NDIM + cw * 128 + ml;
                #pragma unroll
                for (int ct = 0; ct < 8; ++ct)
                    op[ct * 16] = acc[ct][rgi];
            }
        }
    }
}

__global__ __launch_bounds__(256) void k_reduce(
    const float* __restrict__ ws,
    float*       __restrict__ out,
    int n_rows)
{
    const int i = blockIdx.x * 256 + threadIdx.x;     // float4 index
    const int total = n_rows * (NDIM / 4);
    if (i < total) {
        const f32x4* a = (const f32x4*)ws;
        const int S = total;                          // per-kq stride in float4
        f32x4 v = a[i] + a[i + S] + a[i + 2 * S] + a[i + 3 * S];
        ((f32x4*)out)[i] = v;
    }
}

extern "C" void kernel_launch(void* const* d_in, const int* in_sizes, int n_in,
                              void* d_out, int out_size, void* d_ws, size_t ws_size,
                              hipStream_t stream) {
    const float* x    = (const float*)d_in[0];
    const int*   tids = (const int*)d_in[1];
    const float* W    = (const float*)d_in[2];
    float*       out  = (float*)d_out;
    float*       ws   = (float*)d_ws;
    const int n_rows  = in_sizes[1];   // 2048

    k_split<<<dim3(256), dim3(512), 0, stream>>>(x, tids, W, ws, n_rows);

    const int total4 = n_rows * (NDIM / 4);
    k_reduce<<<dim3((total4 + 255) / 256), dim3(256), 0, stream>>>(ws, out, n_rows);
}

// Round 12
// 102.657 us; speedup vs baseline: 1.7867x; 1.0703x over previous
//
#include <hip/hip_runtime.h>

// LearnedTaskSpecificLinear: out[n,o] = sum_i x[n,i] * W[task_ids[n], i, o]
// x: [2048,512] f32, task_ids: [2048] i32, W: [64,512,512] f32, out: [2048,512] f32
//
// Round 15: REVERT to Round 12 (best measured: 104.8 us total, ~22.6 us kernel).
//   Session conclusion: schedule (R5-R9), barriers (R10), occupancy (R7-R11),
//   granule (R12), and contiguity (R14 split-K) all probed; kernel time pinned
//   at 22.6-27.7 us across every structure (~3.1-3.7 TB/s effective cold-HBM
//   read). R12's 64-col x 256-k unit form is the best point found.
//
//   Unit = task x 64-col chunk (8 chunks/task, 512 blocks x 256 thr, 1 unit
//   each). Each 16-lane group reads 256 B contiguous W per k-row.
//   LDS: Wt[2][64x256] f16 (64 KB) + lists -> 2 blocks/CU.
//   launch_bounds(256,2): VGPR cap 256, audited peak ~180 - no spill.
//   Schedule = R8/R9's proven 2-buffer form: issue h0{s0->A,s1->B} -> scan ->
//   x-h0 gather (covers latency) -> stage A, issue h1s0->A -> stage B, issue
//   h1s1->B -> [lgkmcnt(0); s_barrier] -> mma(h0) + x-h1 gather -> stage h1
//   -> [lgkmcnt(0); s_barrier] -> mma(h1) + store. No vmcnt drain at barriers.
//   Swizzle po = oct ^ (c&7) and all fragment/store mappings verified R5-R12.

#define NDIM 512
#define KDIM 512
#define NCOL 64
#define KH   256
#define GRID 512

typedef _Float16 f16x8 __attribute__((ext_vector_type(8)));
typedef float    f32x4 __attribute__((ext_vector_type(4)));
typedef int      i32x4 __attribute__((ext_vector_type(4)));

__global__ __launch_bounds__(256, 2) void k_g64(
    const float* __restrict__ x,
    const int*   __restrict__ tids,
    const float* __restrict__ W,
    float*       __restrict__ out,
    int n_rows)
{
    const int tid  = threadIdx.x;
    const int lane = tid & 63;
    const int wv   = tid >> 6;
    const int ml   = lane & 15;
    const int q    = lane >> 4;
    const int cg   = tid & 15;          // col group 0..15 (4 cols each -> 64 cols)
    const int sc4  = cg * 4;
    const int ot   = tid >> 4;          // base k-octet 0..15; stripes ot, ot+16

    // decode: task's 8 chunks all share bid&7 -> one XCD (x rows L2-resident)
    const int bid   = blockIdx.x;
    const int task  = (bid & 7) | ((bid >> 6) << 3);
    const int c0    = ((bid >> 3) & 7) * NCOL;

    __shared__ __align__(16) _Float16 Wt[2][NCOL * KH];   // 2 x 32 KB, swizzled
    __shared__ unsigned short rlw[4 * 128];               // per-wave private lists

    const float* Wg = W + (size_t)task * KDIM * NDIM + c0;

    // ---- tids: 8 consecutive rows per lane (this wave's 512-row quarter)
    const int rbase = wv * 512 + lane * 8;
    int tval[8];
    if (rbase + 7 < n_rows) {
        const i32x4 a = *(const i32x4*)(tids + rbase);
        const i32x4 b = *(const i32x4*)(tids + rbase + 4);
        tval[0] = a[0]; tval[1] = a[1]; tval[2] = a[2]; tval[3] = a[3];
        tval[4] = b[0]; tval[5] = b[1]; tval[6] = b[2]; tval[7] = b[3];
    } else {
        #pragma unroll
        for (int j = 0; j < 8; ++j)
            tval[j] = (rbase + j < n_rows) ? tids[rbase + j] : -1;
    }

    float4 wrA[8], wrB[8];

    // stripe (h, s): k-octet oct = ot + 16*s of K-half h; 8 rows x 16 B/thread.
    // Coalescing: 16 lanes (cg 0..15) cover 64 cols = 256 B contiguous per row.
    auto issueS = [&](int h, int s, float4 (&wb)[8]) {
        const size_t kb = (size_t)(h * KH) + (size_t)(ot + 16 * s) * 8;
        #pragma unroll
        for (int j = 0; j < 8; ++j)
            wb[j] = *(const float4*)(Wg + (kb + j) * NDIM + sc4);
    };
    auto stageS = [&](int h, int s, const float4 (&wb)[8]) {
        const int oct = ot + 16 * s;
        #pragma unroll
        for (int j2 = 0; j2 < 4; ++j2) {
            f16x8 h8;
            #pragma unroll
            for (int j = 0; j < 8; ++j)
                h8[j] = (_Float16)(((const float*)&wb[j])[j2]);
            const int c  = sc4 + j2;
            const int po = oct ^ (c & 7);
            *(f16x8*)&Wt[h][c * KH + po * 8] = h8;
        }
    };

    // ---- issue both stripes of K-half 0 up front
    issueS(0, 0, wrA);
    issueS(0, 1, wrB);

    // ---- ballot scan -> per-wave private row list (covers W h0 latency)
    int cloc = 0;
    #pragma unroll
    for (int j = 0; j < 8; ++j) {
        const bool m = (tval[j] == task);
        const unsigned long long bal = __ballot(m);
        const int rank = __popcll(bal & ((1ull << lane) - 1ull));
        const int slot = cloc + rank;
        if (m && slot < 128) rlw[wv * 128 + slot] = (unsigned short)(rbase + j);
        cloc += __popcll(bal);
    }
    if (cloc > 128) cloc = 128;

    auto load_half = [&](const float* xrp, int t, f16x8* paf) {
        #pragma unroll
        for (int h = 0; h < 2; ++h) {
            f32x4 xa[8];
            #pragma unroll
            for (int k2 = 0; k2 < 4; ++k2) {
                const int ks = h * 4 + k2;
                xa[2 * k2]     = *(const f32x4*)(xrp + t * KH + ks * 32 + q * 8);
                xa[2 * k2 + 1] = *(const f32x4*)(xrp + t * KH + ks * 32 + q * 8 + 4);
            }
            #pragma unroll
            for (int k2 = 0; k2 < 4; ++k2) {
                f16x8 af;
                const float* a0 = (const float*)&xa[2 * k2];
                #pragma unroll
                for (int j = 0; j < 8; ++j) af[j] = (_Float16)a0[j];
                paf[h * 4 + k2] = af;
            }
        }
    };

    auto mma_half = [&](int t, const f16x8* paf, f32x4* acc) {
        #pragma unroll
        for (int ks = 0; ks < 8; ++ks) {
            #pragma unroll
            for (int ct = 0; ct < 4; ++ct) {
                const int cB = ct * 16 + ml;
                const int po = (ks * 4 + q) ^ (cB & 7);
                const f16x8 bf = *(const f16x8*)&Wt[t][cB * KH + po * 8];
                acc[ct] = __builtin_amdgcn_mfma_f32_16x16x32_f16(paf[ks], bf, acc[ct], 0, 0, 0);
            }
        }
    };

    auto store_rows = [&](int g0, const f32x4* acc) {
        #pragma unroll
        for (int rg = 0; rg < 4; ++rg) {
            const int pos = g0 + q * 4 + rg;
            if (pos < cloc) {
                float* op = out + (size_t)rlw[wv * 128 + pos] * NDIM + c0 + ml;
                op[0]  = acc[0][rg];
                op[16] = acc[1][rg];
                op[32] = acc[2][rg];
                op[48] = acc[3][rg];
            }
        }
    };

    // ---- x half-0 gather (clamped dup addresses -> coalesced, no extra traffic)
    const float* xr = x;
    f16x8 pafA[8], pafB[8];
    if (cloc > 0) {
        const int idx = (ml < cloc) ? ml : (cloc - 1);
        xr = x + (size_t)rlw[wv * 128 + idx] * KDIM;
        load_half(xr, 0, pafA);
    }

    // ---- stage h0 stripes; refill buffers with h1 stripes (2-buffer stream)
    stageS(0, 0, wrA);
    issueS(1, 0, wrA);
    stageS(0, 1, wrB);
    issueS(1, 1, wrB);

    asm volatile("s_waitcnt lgkmcnt(0)" ::: "memory");
    __builtin_amdgcn_s_barrier();
    __builtin_amdgcn_sched_barrier(0);

    // ---- half-0 MFMA (hides h1 stripe latency), x half-1 gather
    f32x4 acc[4] = {};
    if (cloc > 0) mma_half(0, pafA, acc);
    if (cloc > 0) load_half(xr, 1, pafB);

    stageS(1, 0, wrA);
    stageS(1, 1, wrB);

    asm volatile("s_waitcnt lgkmcnt(0)" ::: "memory");
    __builtin_amdgcn_s_barrier();
    __builtin_amdgcn_sched_barrier(0);

    // ---- half-1 MFMA + store
    if (cloc > 0) {
        mma_half(1, pafB, acc);
        store_rows(0, acc);
    }

    // ---- rare: wave quarter with >16 matching rows; both Wt halves resident
    for (int g0 = 16; g0 < cloc; g0 += 16) {
        const int idx = g0 + ml;
        const float* xr2 = x + (size_t)rlw[wv * 128 + ((idx < cloc) ? idx : (cloc - 1))] * KDIM;
        f16x8 pf[8];
        f32x4 a2[4] = {};
        load_half(xr2, 0, pf);
        mma_half(0, pf, a2);
        load_half(xr2, 1, pf);
        mma_half(1, pf, a2);
        store_rows(g0, a2);
    }
}

extern "C" void kernel_launch(void* const* d_in, const int* in_sizes, int n_in,
                              void* d_out, int out_size, void* d_ws, size_t ws_size,
                              hipStream_t stream) {
    const float* x    = (const float*)d_in[0];
    const int*   tids = (const int*)d_in[1];
    const float* W    = (const float*)d_in[2];
    float*       out  = (float*)d_out;
    const int n_rows  = in_sizes[1];   // 2048

    k_g64<<<dim3(GRID), dim3(256), 0, stream>>>(x, tids, W, out, n_rows);
}